// Round 1
// baseline (78.888 us; speedup 1.0000x reference)
//
#include <hip/hip_runtime.h>
#include <hip/hip_bf16.h>

#define NN 8192

// Phase 1: split-K GEMV partials.  partial[s][j] = sum over rows r0..r0+rps of g_i * w[i][j]
// Grid: x = column tile (1024 cols each), y = row split s.
__global__ __launch_bounds__(256) void lif_gemv_part(
    const float* __restrict__ g, const float* __restrict__ w,
    float* __restrict__ partial, int rows_per_split)
{
    const int col = blockIdx.x * 1024 + threadIdx.x * 4;
    const int s   = blockIdx.y;
    const int r0  = s * rows_per_split;

    const float* wp = w + (size_t)r0 * NN + col;
    const float* gp = g + r0;

    float4 acc = make_float4(0.f, 0.f, 0.f, 0.f);
    #pragma unroll 8
    for (int i = 0; i < rows_per_split; ++i) {
        const float  gi = gp[i];                               // uniform -> scalar load, L1/L2 hit
        const float4 wv = *reinterpret_cast<const float4*>(wp + (size_t)i * NN);
        acc.x = fmaf(gi, wv.x, acc.x);
        acc.y = fmaf(gi, wv.y, acc.y);
        acc.z = fmaf(gi, wv.z, acc.z);
        acc.w = fmaf(gi, wv.w, acc.w);
    }
    *reinterpret_cast<float4*>(partial + (size_t)s * NN + col) = acc;
}

// Phase 2: deterministic reduction over splits + LIF pointwise.
__global__ __launch_bounds__(256) void lif_pointwise(
    const float* __restrict__ partial, int nsplits,
    const float* __restrict__ x_in, const float* __restrict__ v,
    const float* __restrict__ E_L, const float* __restrict__ tau_m,
    float* __restrict__ out)
{
    const int j = blockIdx.x * blockDim.x + threadIdx.x;
    if (j >= NN) return;

    float I = 0.f;
    for (int s = 0; s < nsplits; ++s)          // sequential: deterministic order
        I += partial[(size_t)s * NN + j];

    // I = sigmoid(2*6*I/N) + 0.9*x_in
    const float arg  = 12.0f * I / 8192.0f;
    const float Isig = 1.0f / (1.0f + expf(-arg));
    const float Ifull = Isig + 0.9f * x_in[j];

    const float el  = E_L[j];
    const float vv  = v[j];
    const float norm_R_f = 30.0f - el;
    const float v_next = vv + (el - vv + Ifull * norm_R_f) / tau_m[j];

    // sigmoid(v_next - 30)
    out[j] = 1.0f / (1.0f + expf(30.0f - v_next));
}

extern "C" void kernel_launch(void* const* d_in, const int* in_sizes, int n_in,
                              void* d_out, int out_size, void* d_ws, size_t ws_size,
                              hipStream_t stream) {
    const float* x_in  = (const float*)d_in[0];
    const float* v     = (const float*)d_in[1];
    const float* g     = (const float*)d_in[2];
    const float* w     = (const float*)d_in[3];
    const float* E_L   = (const float*)d_in[4];
    const float* tau_m = (const float*)d_in[5];
    // d_in[6] = tau_g, unused by the reference
    float* out     = (float*)d_out;
    float* partial = (float*)d_ws;

    // Pick the largest power-of-2 split count that fits the workspace.
    int S = 128;
    while (S > 1 && (size_t)S * NN * sizeof(float) > ws_size) S >>= 1;
    const int rps = NN / S;

    dim3 grid1(NN / 1024, S);
    lif_gemv_part<<<grid1, 256, 0, stream>>>(g, w, partial, rps);
    lif_pointwise<<<NN / 256, 256, 0, stream>>>(partial, S, x_in, v, E_L, tau_m, out);
}